// Round 1
// baseline (2081.254 us; speedup 1.0000x reference)
//
#include <hip/hip_runtime.h>
#include <math.h>

#define B_   8
#define C_   256
#define CI_  128
#define N_   4096
#define O3_  384

// workspace layout (float offsets)
#define OFF_P   0ull                    // [B][384][N]: rows 0-127 g_x, 128-255 theta, 256-383 phi
#define OFF_Y   12582912ull             // [B][128][N]
#define OFF_WY  16777216ull             // [B][256][N]
#define OFF_ST  25165824ull             // [2][256] mean, inv_std
#define OFF_W3  25166336ull             // [384][256]
#define OFF_B3  25264640ull             // [384]
// total floats: 25,265,024 (~101 MB)

__global__ __launch_bounds__(256) void pack_w(
    const float* __restrict__ g_w, const float* __restrict__ g_b,
    const float* __restrict__ th_w, const float* __restrict__ th_b,
    const float* __restrict__ ph_w, const float* __restrict__ ph_b,
    float* __restrict__ W3, float* __restrict__ b3)
{
  int i = blockIdx.x * 256 + threadIdx.x;   // < 384*256
  int o = i >> 8;
  float v;
  if (o < 128)      v = g_w[i];
  else if (o < 256) v = th_w[i - 128*256];
  else              v = ph_w[i - 256*256];
  W3[i] = v;
  if ((i & 255) == 0) {
    b3[o] = (o < 128) ? g_b[o] : (o < 256) ? th_b[o - 128] : ph_b[o - 256];
  }
}

// Out[b][o][n] = sum_k A[o][k] * X[b][k][n] + bias[o]
// grid: (N/64, Odim/64, B), block 256. Tile 64x64, K-step 16, 4x4 per thread.
__global__ __launch_bounds__(256) void gemm_bias(
    const float* __restrict__ A, const float* __restrict__ bias,
    const float* __restrict__ X, float* __restrict__ Out,
    int Odim, int Kdim)
{
  const int b  = blockIdx.z;
  const int o0 = blockIdx.y * 64;
  const int n0 = blockIdx.x * 64;
  const int tid = threadIdx.x;
  __shared__ float As[16 * 68];
  __shared__ float Xs[16 * 68];
  const int ty = tid >> 4, tx = tid & 15;
  float acc[4][4] = {};
  const float* Xb = X + (size_t)b * Kdim * N_;

  const int lkA = tid & 15, loA = tid >> 4;   // A-tile load coords
  const int lnX = tid & 63, lkX = tid >> 6;   // X-tile load coords

  for (int k0 = 0; k0 < Kdim; k0 += 16) {
    #pragma unroll
    for (int r = 0; r < 4; ++r)
      As[lkA * 68 + loA + 16 * r] = A[(size_t)(o0 + loA + 16 * r) * Kdim + k0 + lkA];
    #pragma unroll
    for (int r = 0; r < 4; ++r)
      Xs[(lkX + 4 * r) * 68 + lnX] = Xb[(size_t)(k0 + lkX + 4 * r) * N_ + n0 + lnX];
    __syncthreads();
    #pragma unroll
    for (int k = 0; k < 16; ++k) {
      float4 a4 = *(const float4*)&As[k * 68 + ty * 4];
      float4 x4 = *(const float4*)&Xs[k * 68 + tx * 4];
      float av[4] = {a4.x, a4.y, a4.z, a4.w};
      float xv[4] = {x4.x, x4.y, x4.z, x4.w};
      #pragma unroll
      for (int i = 0; i < 4; ++i)
        #pragma unroll
        for (int j = 0; j < 4; ++j)
          acc[i][j] += av[i] * xv[j];
    }
    __syncthreads();
  }
  #pragma unroll
  for (int i = 0; i < 4; ++i) {
    int o = o0 + ty * 4 + i;
    float bv = bias[o];
    float4 v = make_float4(acc[i][0] + bv, acc[i][1] + bv, acc[i][2] + bv, acc[i][3] + bv);
    *(float4*)&Out[((size_t)b * Odim + o) * N_ + n0 + tx * 4] = v;
  }
}

// Flash attention: per (b, 64-query tile). Streams 64-key tiles, online softmax,
// y accumulated in registers (32 floats/thread: q = tid&63, c = (tid>>6)*32 + j).
#define LSTR 68
__global__ __launch_bounds__(256) void attn_flash(
    const float* __restrict__ P, float* __restrict__ Y)
{
  const int b  = blockIdx.y;
  const int q0 = blockIdx.x * 64;
  const int tid = threadIdx.x;

  __shared__ float th_s[CI_ * LSTR];
  __shared__ float ph_s[CI_ * LSTR];
  __shared__ float g_s [CI_ * LSTR];
  __shared__ float s_t [64 * LSTR];
  __shared__ float alpha_s[64], nm_s[64], psum_s[64 * 4], l_s[64];

  const float* Pb  = P + (size_t)b * O3_ * N_;
  const float* Gp  = Pb;                         // rows 0..127   : g_x
  const float* THp = Pb + (size_t)CI_ * N_;      // rows 128..255 : theta
  const float* PHp = Pb + (size_t)2 * CI_ * N_;  // rows 256..383 : phi

  // stage theta tile [128 c][64 q]
  for (int idx = tid; idx < CI_ * 64; idx += 256) {
    int c = idx >> 6, q = idx & 63;
    th_s[c * LSTR + q] = THp[(size_t)c * N_ + q0 + q];
  }

  float m_run = -INFINITY, l_run = 0.f;
  float acc[32];
  #pragma unroll
  for (int j = 0; j < 32; ++j) acc[j] = 0.f;

  const int qo = tid & 63;
  const int cb = (tid >> 6) * 32;
  const int ty = tid >> 4, tx = tid & 15;

  for (int m0 = 0; m0 < N_; m0 += 64) {
    for (int idx = tid; idx < CI_ * 64; idx += 256) {
      int c = idx >> 6, m = idx & 63;
      ph_s[c * LSTR + m] = PHp[(size_t)c * N_ + m0 + m];
      g_s [c * LSTR + m] = Gp [(size_t)c * N_ + m0 + m];
    }
    __syncthreads();

    // S[q][m] = sum_c th[c][q] * ph[c][m]; 4x4 per thread (q = ty*4+i, m = tx*4+j)
    float sa[4][4] = {};
    #pragma unroll 4
    for (int c = 0; c < CI_; ++c) {
      float4 a4 = *(const float4*)&th_s[c * LSTR + ty * 4];
      float4 b4 = *(const float4*)&ph_s[c * LSTR + tx * 4];
      float av[4] = {a4.x, a4.y, a4.z, a4.w};
      float bv[4] = {b4.x, b4.y, b4.z, b4.w};
      #pragma unroll
      for (int i = 0; i < 4; ++i)
        #pragma unroll
        for (int j = 0; j < 4; ++j)
          sa[i][j] += av[i] * bv[j];
    }
    #pragma unroll
    for (int i = 0; i < 4; ++i)
      *(float4*)&s_t[(ty * 4 + i) * LSTR + tx * 4] =
          make_float4(sa[i][0], sa[i][1], sa[i][2], sa[i][3]);
    __syncthreads();

    // per-q tile max + rescale factor (wave 0)
    if (tid < 64) {
      float tm = -INFINITY;
      for (int m = 0; m < 64; m += 4) {
        float4 v = *(const float4*)&s_t[tid * LSTR + m];
        tm = fmaxf(tm, fmaxf(fmaxf(v.x, v.y), fmaxf(v.z, v.w)));
      }
      float nm = fmaxf(m_run, tm);
      alpha_s[tid] = __expf(m_run - nm);
      nm_s[tid] = nm;
      m_run = nm;
    }
    __syncthreads();

    // exp (all 256 threads: 16 entries each), partial row sums
    {
      float nm = nm_s[qo];
      float ps = 0.f;
      int mb = (tid >> 6) * 16;
      #pragma unroll
      for (int u = 0; u < 16; u += 4) {
        float4 v = *(float4*)&s_t[qo * LSTR + mb + u];
        v.x = __expf(v.x - nm); v.y = __expf(v.y - nm);
        v.z = __expf(v.z - nm); v.w = __expf(v.w - nm);
        ps += v.x + v.y + v.z + v.w;
        *(float4*)&s_t[qo * LSTR + mb + u] = v;
      }
      psum_s[qo * 4 + (tid >> 6)] = ps;
    }
    __syncthreads();

    if (tid < 64)
      l_run = l_run * alpha_s[tid] +
              (psum_s[tid * 4] + psum_s[tid * 4 + 1] + psum_s[tid * 4 + 2] + psum_s[tid * 4 + 3]);

    // y accumulation: acc[j] (c = cb+j) over this m-tile; g reads are wave-broadcast
    {
      float al = alpha_s[qo];
      #pragma unroll
      for (int j = 0; j < 32; ++j) acc[j] *= al;
      for (int mm = 0; mm < 64; mm += 4) {
        float4 p4 = *(const float4*)&s_t[qo * LSTR + mm];
        #pragma unroll
        for (int j = 0; j < 32; ++j) {
          float4 g4 = *(const float4*)&g_s[(cb + j) * LSTR + mm];
          acc[j] += p4.x * g4.x + p4.y * g4.y + p4.z * g4.z + p4.w * g4.w;
        }
      }
    }
    __syncthreads();
  }

  if (tid < 64) l_s[tid] = l_run;
  __syncthreads();
  float inv_l = 1.0f / l_s[qo];
  #pragma unroll
  for (int j = 0; j < 32; ++j)
    Y[((size_t)b * CI_ + cb + j) * N_ + q0 + qo] = acc[j] * inv_l;
}

// per-channel batch-norm stats over (B, N): mean and rsqrt(var+eps)
__global__ __launch_bounds__(256) void bn_stats(
    const float* __restrict__ WY, float* __restrict__ st)
{
  const int o = blockIdx.x;
  const int tid = threadIdx.x;
  float s = 0.f, s2 = 0.f;
  for (int b = 0; b < B_; ++b) {
    const float* p = WY + ((size_t)b * C_ + o) * N_;
    for (int n = tid * 4; n < N_; n += 256 * 4) {
      float4 v = *(const float4*)&p[n];
      s  += v.x + v.y + v.z + v.w;
      s2 += v.x * v.x + v.y * v.y + v.z * v.z + v.w * v.w;
    }
  }
  __shared__ float rs[256], rs2[256];
  rs[tid] = s; rs2[tid] = s2;
  __syncthreads();
  for (int off = 128; off > 0; off >>= 1) {
    if (tid < off) { rs[tid] += rs[tid + off]; rs2[tid] += rs2[tid + off]; }
    __syncthreads();
  }
  if (tid == 0) {
    const float M = (float)(B_ * N_);
    float mean = rs[0] / M;
    float var  = rs2[0] / M - mean * mean;
    st[o] = mean;
    st[256 + o] = rsqrtf(var + 1e-5f);
  }
}

__global__ __launch_bounds__(256) void bn_apply(
    const float* __restrict__ WY, const float* __restrict__ x,
    const float* __restrict__ st, const float* __restrict__ gamma,
    const float* __restrict__ beta, float* __restrict__ out)
{
  size_t i = ((size_t)blockIdx.x * 256 + threadIdx.x) * 4;
  int o = (int)((i >> 12) & 255);
  float4 w  = *(const float4*)&WY[i];
  float4 xv = *(const float4*)&x[i];
  float gsc = gamma[o] * st[256 + o];
  float bb  = beta[o] - st[o] * gsc;
  float4 v;
  v.x = w.x * gsc + bb + xv.x;
  v.y = w.y * gsc + bb + xv.y;
  v.z = w.z * gsc + bb + xv.z;
  v.w = w.w * gsc + bb + xv.w;
  *(float4*)&out[i] = v;
}

extern "C" void kernel_launch(void* const* d_in, const int* in_sizes, int n_in,
                              void* d_out, int out_size, void* d_ws, size_t ws_size,
                              hipStream_t stream)
{
  const float* x       = (const float*)d_in[0];
  const float* g_w     = (const float*)d_in[1];
  const float* g_b     = (const float*)d_in[2];
  const float* theta_w = (const float*)d_in[3];
  const float* theta_b = (const float*)d_in[4];
  const float* phi_w   = (const float*)d_in[5];
  const float* phi_b   = (const float*)d_in[6];
  const float* W_w     = (const float*)d_in[7];
  const float* W_b     = (const float*)d_in[8];
  const float* gamma   = (const float*)d_in[9];
  const float* beta    = (const float*)d_in[10];
  float* out = (float*)d_out;

  float* ws = (float*)d_ws;
  float* P  = ws + OFF_P;
  float* Yb = ws + OFF_Y;
  float* WY = ws + OFF_WY;
  float* ST = ws + OFF_ST;
  float* W3 = ws + OFF_W3;
  float* b3 = ws + OFF_B3;

  pack_w<<<384, 256, 0, stream>>>(g_w, g_b, theta_w, theta_b, phi_w, phi_b, W3, b3);
  gemm_bias<<<dim3(64, 6, 8), 256, 0, stream>>>(W3, b3, x, P, O3_, C_);
  attn_flash<<<dim3(64, 8), 256, 0, stream>>>(P, Yb);
  gemm_bias<<<dim3(64, 4, 8), 256, 0, stream>>>(W_w, W_b, Yb, WY, C_, CI_);
  bn_stats<<<256, 256, 0, stream>>>(WY, ST);
  bn_apply<<<8192, 256, 0, stream>>>(WY, x, ST, gamma, beta, out);
}

// Round 2
// 534.486 us; speedup vs baseline: 3.8939x; 3.8939x over previous
//
#include <hip/hip_runtime.h>
#include <math.h>

#define B_   8
#define C_   256
#define CI_  128
#define N_   4096
#define O3_  384

typedef unsigned short ushort_t;
typedef unsigned int uint_t;
typedef __attribute__((ext_vector_type(8))) short short8;
typedef __attribute__((ext_vector_type(4))) float floatx4;

// workspace layout (byte offsets)
#define OFF_W3   0ull          // fp32 [384][256]        393216 B
#define OFF_B3   393216ull     // fp32 [384]             1536 B
#define OFF_THT  394752ull     // bf16 [B][N][128]       8388608 B
#define OFF_PHT  8783360ull    // bf16 [B][N][128]       8388608 B
#define OFF_G16  17171968ull   // bf16 [B][128][N]       8388608 B
#define OFF_YT   25560576ull   // fp32 [B][N][128]       16777216 B
#define OFF_WY   42337792ull   // fp32 [B][256][N]       33554432 B
#define OFF_ST   75892224ull   // fp32 [2][256]          2048 B
// total ~75.9 MB

__device__ __forceinline__ ushort_t f2bf(float x) {
  union { float f; uint_t u; } c; c.f = x;
  uint_t r = (c.u + 0x7fffu + ((c.u >> 16) & 1u)) >> 16;
  return (ushort_t)r;
}

__global__ __launch_bounds__(256) void pack_w(
    const float* __restrict__ g_w, const float* __restrict__ g_b,
    const float* __restrict__ th_w, const float* __restrict__ th_b,
    const float* __restrict__ ph_w, const float* __restrict__ ph_b,
    float* __restrict__ W3, float* __restrict__ b3)
{
  int i = blockIdx.x * 256 + threadIdx.x;   // < 384*256
  int o = i >> 8;
  float v;
  if (o < 128)      v = g_w[i];
  else if (o < 256) v = th_w[i - 128*256];
  else              v = ph_w[i - 256*256];
  W3[i] = v;
  if ((i & 255) == 0) {
    b3[o] = (o < 128) ? g_b[o] : (o < 256) ? th_b[o - 128] : ph_b[o - 256];
  }
}

// Projection GEMM: P[o][n] = sum_k W3[o][k] x[b][k][n] + b3[o], fp32 math.
// Epilogue routes to bf16 outputs:
//   o in [0,128)   -> g16[b][o][n]          (c-major)
//   o in [128,256) -> tht[b][n][o-128]      (n-major)
//   o in [256,384) -> pht[b][n][o-256]      (n-major)
__global__ __launch_bounds__(256) void proj_gemm(
    const float* __restrict__ A, const float* __restrict__ bias,
    const float* __restrict__ X, ushort_t* __restrict__ tht,
    ushort_t* __restrict__ pht, ushort_t* __restrict__ g16)
{
  const int b  = blockIdx.z;
  const int o0 = blockIdx.y * 64;
  const int n0 = blockIdx.x * 64;
  const int tid = threadIdx.x;
  __shared__ float As[16 * 68];
  __shared__ float Xs[16 * 68];
  const int ty = tid >> 4, tx = tid & 15;
  float acc[4][4] = {};
  const float* Xb = X + (size_t)b * C_ * N_;

  const int lkA = tid & 15, loA = tid >> 4;
  const int lnX = tid & 63, lkX = tid >> 6;

  for (int k0 = 0; k0 < C_; k0 += 16) {
    #pragma unroll
    for (int r = 0; r < 4; ++r)
      As[lkA * 68 + loA + 16 * r] = A[(size_t)(o0 + loA + 16 * r) * C_ + k0 + lkA];
    #pragma unroll
    for (int r = 0; r < 4; ++r)
      Xs[(lkX + 4 * r) * 68 + lnX] = Xb[(size_t)(k0 + lkX + 4 * r) * N_ + n0 + lnX];
    __syncthreads();
    #pragma unroll
    for (int k = 0; k < 16; ++k) {
      float4 a4 = *(const float4*)&As[k * 68 + ty * 4];
      float4 x4 = *(const float4*)&Xs[k * 68 + tx * 4];
      float av[4] = {a4.x, a4.y, a4.z, a4.w};
      float xv[4] = {x4.x, x4.y, x4.z, x4.w};
      #pragma unroll
      for (int i = 0; i < 4; ++i)
        #pragma unroll
        for (int j = 0; j < 4; ++j)
          acc[i][j] += av[i] * xv[j];
    }
    __syncthreads();
  }
  #pragma unroll
  for (int i = 0; i < 4; ++i) {
    float bv = bias[o0 + ty * 4 + i];
    #pragma unroll
    for (int j = 0; j < 4; ++j) acc[i][j] += bv;
  }

  if (o0 < 128) {
    ushort_t* gp = g16 + (size_t)b * CI_ * N_;
    #pragma unroll
    for (int i = 0; i < 4; ++i) {
      ushort4 u = make_ushort4(f2bf(acc[i][0]), f2bf(acc[i][1]),
                               f2bf(acc[i][2]), f2bf(acc[i][3]));
      *(ushort4*)&gp[(size_t)(o0 + ty * 4 + i) * N_ + n0 + tx * 4] = u;
    }
  } else {
    ushort_t* tp = (o0 < 256) ? (tht + (size_t)b * N_ * CI_)
                              : (pht + (size_t)b * N_ * CI_);
    int ob = ((o0 < 256) ? (o0 - 128) : (o0 - 256)) + ty * 4;
    #pragma unroll
    for (int j = 0; j < 4; ++j) {
      ushort4 u = make_ushort4(f2bf(acc[0][j]), f2bf(acc[1][j]),
                               f2bf(acc[2][j]), f2bf(acc[3][j]));
      *(ushort4*)&tp[(size_t)(n0 + tx * 4 + j) * CI_ + ob] = u;
    }
  }
}

// MFMA flash attention. Block: 64 queries, 4 waves; wave w owns q-rows [w*16, w*16+16).
// S = theta^T phi via mfma_f32_16x16x32_bf16; online softmax per wave; P -> LDS bf16;
// y[q][c] += P * g^T via MFMA. Writes yt[b][n][c] fp32.
__global__ __launch_bounds__(256) void attn_mfma(
    const ushort_t* __restrict__ tht, const ushort_t* __restrict__ pht,
    const ushort_t* __restrict__ g16, float* __restrict__ yt)
{
  const int bidx = blockIdx.x;
  const int b  = bidx & 7;                 // XCD-swizzle: batch -> XCD
  const int q0 = (bidx >> 3) * 64;
  const int tid  = threadIdx.x;
  const int lane = tid & 63;
  const int wq   = (tid >> 6) * 16;        // wave's q-row base
  const int ln15 = lane & 15;
  const int lk8  = (lane >> 4) * 8;
  const int lq4  = (lane >> 4) * 4;

  __shared__ ushort_t phs[64 * 136];       // [m][c] padded
  __shared__ ushort_t gs [128 * 72];       // [c][m] padded
  __shared__ ushort_t ps [64 * 72];        // [q][m] padded

  const ushort_t* thb = tht + (size_t)b * N_ * CI_;
  const ushort_t* phb = pht + (size_t)b * N_ * CI_;
  const ushort_t* gbp = g16 + (size_t)b * CI_ * N_;
  float* ytb = yt + (size_t)b * N_ * CI_;

  // theta A-fragments, register-resident for whole block
  short8 afrag[4];
  #pragma unroll
  for (int k = 0; k < 4; ++k)
    afrag[k] = *(const short8*)&thb[(size_t)(q0 + wq + ln15) * CI_ + k * 32 + lk8];

  floatx4 acc[8];
  #pragma unroll
  for (int ct = 0; ct < 8; ++ct) acc[ct] = (floatx4){0.f, 0.f, 0.f, 0.f};
  float m_run[4] = {-INFINITY, -INFINITY, -INFINITY, -INFINITY};
  float l_run[4] = {0.f, 0.f, 0.f, 0.f};

  for (int m0 = 0; m0 < N_; m0 += 64) {
    // prefetch staging data to regs (overlaps prior iter's PV)
    uint4 phv[4], gv[4];
    #pragma unroll
    for (int r = 0; r < 4; ++r) {
      int id = tid + 256 * r;
      phv[r] = *(const uint4*)&phb[(size_t)(m0 + (id >> 4)) * CI_ + (id & 15) * 8];
      gv[r]  = *(const uint4*)&gbp[(size_t)(id >> 3) * N_ + m0 + (id & 7) * 8];
    }
    __syncthreads();   // prior iter's LDS readers done
    #pragma unroll
    for (int r = 0; r < 4; ++r) {
      int id = tid + 256 * r;
      *(uint4*)&phs[(id >> 4) * 136 + (id & 15) * 8] = phv[r];
      *(uint4*)&gs [(id >> 3) * 72  + (id & 7) * 8]  = gv[r];
    }
    __syncthreads();   // staging visible

    // QK^T: S[q][m], wave w computes rows wq..wq+15 x all 64 m
    floatx4 s[4];
    #pragma unroll
    for (int mt = 0; mt < 4; ++mt) s[mt] = (floatx4){0.f, 0.f, 0.f, 0.f};
    #pragma unroll
    for (int k = 0; k < 4; ++k) {
      #pragma unroll
      for (int mt = 0; mt < 4; ++mt) {
        short8 bf = *(const short8*)&phs[(mt * 16 + ln15) * 136 + k * 32 + lk8];
        s[mt] = __builtin_amdgcn_mfma_f32_16x16x32_bf16(afrag[k], bf, s[mt], 0, 0, 0);
      }
    }

    // online softmax (rows fully wave-local; 16-lane butterfly reductions)
    float rmax[4], alpha[4], rsum[4];
    #pragma unroll
    for (int r = 0; r < 4; ++r)
      rmax[r] = fmaxf(fmaxf(s[0][r], s[1][r]), fmaxf(s[2][r], s[3][r]));
    #pragma unroll
    for (int off = 1; off < 16; off <<= 1)
      #pragma unroll
      for (int r = 0; r < 4; ++r)
        rmax[r] = fmaxf(rmax[r], __shfl_xor(rmax[r], off));
    #pragma unroll
    for (int r = 0; r < 4; ++r) {
      float nm = fmaxf(m_run[r], rmax[r]);
      alpha[r] = __expf(m_run[r] - nm);
      m_run[r] = nm;
      rsum[r] = 0.f;
    }
    #pragma unroll
    for (int mt = 0; mt < 4; ++mt) {
      #pragma unroll
      for (int r = 0; r < 4; ++r) {
        float p = __expf(s[mt][r] - m_run[r]);
        rsum[r] += p;
        ps[(wq + lq4 + r) * 72 + mt * 16 + ln15] = f2bf(p);
      }
    }
    #pragma unroll
    for (int off = 1; off < 16; off <<= 1)
      #pragma unroll
      for (int r = 0; r < 4; ++r)
        rsum[r] += __shfl_xor(rsum[r], off);
    #pragma unroll
    for (int r = 0; r < 4; ++r)
      l_run[r] = l_run[r] * alpha[r] + rsum[r];
    #pragma unroll
    for (int ct = 0; ct < 8; ++ct)
      #pragma unroll
      for (int r = 0; r < 4; ++r)
        acc[ct][r] *= alpha[r];

    __syncthreads();   // ps visible (wave-local rows, but cross-lane via LDS)

    // PV: y[q][c] += P[q][m] g[c][m];  A = P rows (wave-local), B = g^T
    short8 pa0 = *(const short8*)&ps[(wq + ln15) * 72 + lk8];
    short8 pa1 = *(const short8*)&ps[(wq + ln15) * 72 + 32 + lk8];
    #pragma unroll
    for (int ct = 0; ct < 8; ++ct) {
      short8 gb0 = *(const short8*)&gs[(ct * 16 + ln15) * 72 + lk8];
      short8 gb1 = *(const short8*)&gs[(ct * 16 + ln15) * 72 + 32 + lk8];
      acc[ct] = __builtin_amdgcn_mfma_f32_16x16x32_bf16(pa0, gb0, acc[ct], 0, 0, 0);
      acc[ct] = __builtin_amdgcn_mfma_f32_16x16x32_bf16(pa1, gb1, acc[ct], 0, 0, 0);
    }
  }

  float inv[4];
  #pragma unroll
  for (int r = 0; r < 4; ++r) inv[r] = 1.0f / l_run[r];
  #pragma unroll
  for (int ct = 0; ct < 8; ++ct)
    #pragma unroll
    for (int r = 0; r < 4; ++r)
      ytb[(size_t)(q0 + wq + lq4 + r) * CI_ + ct * 16 + ln15] = acc[ct][r] * inv[r];
}

// W-conv GEMM consuming transposed y: Out[b][o][n] = sum_c W_w[o][c] yt[b][n][c] + W_b[o]
__global__ __launch_bounds__(256) void wgemm_t(
    const float* __restrict__ A, const float* __restrict__ bias,
    const float* __restrict__ Xt, float* __restrict__ Out)
{
  const int b  = blockIdx.z;
  const int o0 = blockIdx.y * 64;
  const int n0 = blockIdx.x * 64;
  const int tid = threadIdx.x;
  __shared__ float As[16 * 68];
  __shared__ float Xs[16 * 68];
  const int ty = tid >> 4, tx = tid & 15;
  float acc[4][4] = {};
  const float* Xb = Xt + (size_t)b * N_ * CI_;
  const int lkA = tid & 15, loA = tid >> 4;

  for (int k0 = 0; k0 < CI_; k0 += 16) {
    #pragma unroll
    for (int r = 0; r < 4; ++r)
      As[lkA * 68 + loA + 16 * r] = A[(size_t)(o0 + loA + 16 * r) * CI_ + k0 + lkA];
    #pragma unroll
    for (int r = 0; r < 4; ++r)
      Xs[(tid & 15) * 68 + (tid >> 4) + 16 * r] =
          Xb[(size_t)(n0 + (tid >> 4) + 16 * r) * CI_ + k0 + (tid & 15)];
    __syncthreads();
    #pragma unroll
    for (int k = 0; k < 16; ++k) {
      float4 a4 = *(const float4*)&As[k * 68 + ty * 4];
      float4 x4 = *(const float4*)&Xs[k * 68 + tx * 4];
      float av[4] = {a4.x, a4.y, a4.z, a4.w};
      float xv[4] = {x4.x, x4.y, x4.z, x4.w};
      #pragma unroll
      for (int i = 0; i < 4; ++i)
        #pragma unroll
        for (int j = 0; j < 4; ++j)
          acc[i][j] += av[i] * xv[j];
    }
    __syncthreads();
  }
  #pragma unroll
  for (int i = 0; i < 4; ++i) {
    int o = o0 + ty * 4 + i;
    float bv = bias[o];
    float4 v = make_float4(acc[i][0] + bv, acc[i][1] + bv, acc[i][2] + bv, acc[i][3] + bv);
    *(float4*)&Out[((size_t)b * C_ + o) * N_ + n0 + tx * 4] = v;
  }
}

__global__ __launch_bounds__(256) void bn_stats(
    const float* __restrict__ WY, float* __restrict__ st)
{
  const int o = blockIdx.x;
  const int tid = threadIdx.x;
  float s = 0.f, s2 = 0.f;
  for (int b = 0; b < B_; ++b) {
    const float* p = WY + ((size_t)b * C_ + o) * N_;
    for (int n = tid * 4; n < N_; n += 256 * 4) {
      float4 v = *(const float4*)&p[n];
      s  += v.x + v.y + v.z + v.w;
      s2 += v.x * v.x + v.y * v.y + v.z * v.z + v.w * v.w;
    }
  }
  __shared__ float rs[256], rs2[256];
  rs[tid] = s; rs2[tid] = s2;
  __syncthreads();
  for (int off = 128; off > 0; off >>= 1) {
    if (tid < off) { rs[tid] += rs[tid + off]; rs2[tid] += rs2[tid + off]; }
    __syncthreads();
  }
  if (tid == 0) {
    const float M = (float)(B_ * N_);
    float mean = rs[0] / M;
    float var  = rs2[0] / M - mean * mean;
    st[o] = mean;
    st[256 + o] = rsqrtf(var + 1e-5f);
  }
}

__global__ __launch_bounds__(256) void bn_apply(
    const float* __restrict__ WY, const float* __restrict__ x,
    const float* __restrict__ st, const float* __restrict__ gamma,
    const float* __restrict__ beta, float* __restrict__ out)
{
  size_t i = ((size_t)blockIdx.x * 256 + threadIdx.x) * 4;
  int o = (int)((i >> 12) & 255);
  float4 w  = *(const float4*)&WY[i];
  float4 xv = *(const float4*)&x[i];
  float gsc = gamma[o] * st[256 + o];
  float bb  = beta[o] - st[o] * gsc;
  float4 v;
  v.x = w.x * gsc + bb + xv.x;
  v.y = w.y * gsc + bb + xv.y;
  v.z = w.z * gsc + bb + xv.z;
  v.w = w.w * gsc + bb + xv.w;
  *(float4*)&out[i] = v;
}

extern "C" void kernel_launch(void* const* d_in, const int* in_sizes, int n_in,
                              void* d_out, int out_size, void* d_ws, size_t ws_size,
                              hipStream_t stream)
{
  const float* x       = (const float*)d_in[0];
  const float* g_w     = (const float*)d_in[1];
  const float* g_b     = (const float*)d_in[2];
  const float* theta_w = (const float*)d_in[3];
  const float* theta_b = (const float*)d_in[4];
  const float* phi_w   = (const float*)d_in[5];
  const float* phi_b   = (const float*)d_in[6];
  const float* W_w     = (const float*)d_in[7];
  const float* W_b     = (const float*)d_in[8];
  const float* gamma   = (const float*)d_in[9];
  const float* beta    = (const float*)d_in[10];
  float* out = (float*)d_out;

  char* ws = (char*)d_ws;
  float*    W3  = (float*)(ws + OFF_W3);
  float*    b3  = (float*)(ws + OFF_B3);
  ushort_t* tht = (ushort_t*)(ws + OFF_THT);
  ushort_t* pht = (ushort_t*)(ws + OFF_PHT);
  ushort_t* g16 = (ushort_t*)(ws + OFF_G16);
  float*    yt  = (float*)(ws + OFF_YT);
  float*    WY  = (float*)(ws + OFF_WY);
  float*    ST  = (float*)(ws + OFF_ST);

  pack_w<<<384, 256, 0, stream>>>(g_w, g_b, theta_w, theta_b, phi_w, phi_b, W3, b3);
  proj_gemm<<<dim3(64, 6, 8), 256, 0, stream>>>(W3, b3, x, tht, pht, g16);
  attn_mfma<<<512, 256, 0, stream>>>(tht, pht, g16, yt);
  wgemm_t<<<dim3(64, 4, 8), 256, 0, stream>>>(W_w, W_b, yt, WY);
  bn_stats<<<256, 256, 0, stream>>>(WY, ST);
  bn_apply<<<8192, 256, 0, stream>>>(WY, x, ST, gamma, beta, out);
}